// Round 1
// baseline (8573.432 us; speedup 1.0000x reference)
//
#include <hip/hip_runtime.h>

// RNN: B=64, T=512, I=1024, H=1024, fp32.
// Phase 1: xproj = x @ Wx + bx + bh  -> written into d_out (same layout as outs)
// Phase 2: persistent scan kernel; 256 blocks = 8 batch-groups x 32 col-groups.
//   - Wh slice held in REGISTERS (32 float4/lane) for all 512 steps
//   - h exchanged via double-buffered global (d_ws) with per-cluster atomic barrier
//   - cluster = 32 blocks with blockIdx % 8 == bg  (stride 8 -> same XCD likely)

#define Bdim 64
#define Tdim 512
#define Idim 1024
#define Hdim 1024
#define Mdim (Bdim * Tdim)  // 32768

__device__ __forceinline__ float tanh_fast(float x) {
  // tanh(x) = 1 - 2/(e^{2x}+1); correct saturation at +/-inf of exp
  float e = __expf(2.0f * x);
  return 1.0f - 2.0f / (e + 1.0f);
}

// ---------------- Phase 1: xproj GEMM (fp32 SIMT, 128x128 tile, 8x8/thread) --
#define BM 128
#define BN 128
#define BK 16

__global__ __launch_bounds__(256) void xproj_gemm(
    const float* __restrict__ A,   // x  [M=32768][K=1024]
    const float* __restrict__ W,   // Wx [K=1024][N=1024]
    const float* __restrict__ bx,  // [N]
    const float* __restrict__ bh,  // [N]
    float* __restrict__ C) {       // [M][N]
  __shared__ float As[BK][BM];
  __shared__ float Bs[BK][BN];
  const int tid = threadIdx.x;
  const int m0 = blockIdx.y * BM;
  const int n0 = blockIdx.x * BN;
  const int ty = tid >> 4;        // 0..15 -> rows ty*8..+7
  const int tx = tid & 15;        // 0..15 -> cols tx*8..+7
  const int ar = tid & 127;       // stage-A row
  const int ah = tid >> 7;        // stage-A k-half (0/1)
  const int bk = tid >> 4;        // stage-B k-row (0..15)
  const int bs = tid & 15;        // stage-B n-seg

  float acc[8][8];
#pragma unroll
  for (int i = 0; i < 8; ++i)
#pragma unroll
    for (int j = 0; j < 8; ++j) acc[i][j] = 0.f;

  for (int k0 = 0; k0 < Idim; k0 += BK) {
    float4 a0 = *(const float4*)&A[(size_t)(m0 + ar) * Idim + k0 + ah * 8];
    float4 a1 = *(const float4*)&A[(size_t)(m0 + ar) * Idim + k0 + ah * 8 + 4];
    float4 b0 = *(const float4*)&W[(size_t)(k0 + bk) * Hdim + n0 + bs * 8];
    float4 b1 = *(const float4*)&W[(size_t)(k0 + bk) * Hdim + n0 + bs * 8 + 4];
    __syncthreads();  // previous iteration's LDS reads complete
    As[ah * 8 + 0][ar] = a0.x; As[ah * 8 + 1][ar] = a0.y;
    As[ah * 8 + 2][ar] = a0.z; As[ah * 8 + 3][ar] = a0.w;
    As[ah * 8 + 4][ar] = a1.x; As[ah * 8 + 5][ar] = a1.y;
    As[ah * 8 + 6][ar] = a1.z; As[ah * 8 + 7][ar] = a1.w;
    *(float4*)&Bs[bk][bs * 8] = b0;
    *(float4*)&Bs[bk][bs * 8 + 4] = b1;
    __syncthreads();
#pragma unroll
    for (int kk = 0; kk < BK; ++kk) {
      float4 x0 = *(const float4*)&As[kk][ty * 8];
      float4 x1 = *(const float4*)&As[kk][ty * 8 + 4];
      float4 y0 = *(const float4*)&Bs[kk][tx * 8];
      float4 y1 = *(const float4*)&Bs[kk][tx * 8 + 4];
      float av[8] = {x0.x, x0.y, x0.z, x0.w, x1.x, x1.y, x1.z, x1.w};
      float bv[8] = {y0.x, y0.y, y0.z, y0.w, y1.x, y1.y, y1.z, y1.w};
#pragma unroll
      for (int i = 0; i < 8; ++i)
#pragma unroll
        for (int j = 0; j < 8; ++j)
          acc[i][j] = fmaf(av[i], bv[j], acc[i][j]);
    }
  }
  float bias[8];
#pragma unroll
  for (int j = 0; j < 8; ++j) bias[j] = bx[n0 + tx * 8 + j] + bh[n0 + tx * 8 + j];
#pragma unroll
  for (int i = 0; i < 8; ++i) {
    float4 o0, o1;
    o0.x = acc[i][0] + bias[0]; o0.y = acc[i][1] + bias[1];
    o0.z = acc[i][2] + bias[2]; o0.w = acc[i][3] + bias[3];
    o1.x = acc[i][4] + bias[4]; o1.y = acc[i][5] + bias[5];
    o1.z = acc[i][6] + bias[6]; o1.w = acc[i][7] + bias[7];
    size_t off = (size_t)(m0 + ty * 8 + i) * Hdim + n0 + tx * 8;
    *(float4*)&C[off] = o0;
    *(float4*)&C[off + 4] = o1;
  }
}

// ---------------- Phase 2: persistent recurrent scan ------------------------
// block: 256 thr (4 waves). bg = blockIdx%8 (8 batches), cg = blockIdx/8 (32 cols)
// lane mapping: w = tid/64, l = tid%64, kgrp = l/8 (k-chunk of 32), cq = l%8 (col quad)
// lane holds Wh[kbase..kbase+31][cbase+cq*4 ..+3] in 32 float4 registers.
__global__ __launch_bounds__(256, 1) void rnn_scan(
    const float* __restrict__ Wh,   // [H][H] (k-major: Wh[k][c])
    float* out,                     // [B][T][H] : holds xproj, overwritten with h
    float* hlast,                   // [B][H]
    float* hbuf,                    // ws: [2][64][1024]
    unsigned int* ctrs) {           // ws: per-bg counter, 128B apart
  const int bid = blockIdx.x;
  const int bg = bid & 7;
  const int cg = bid >> 3;
  const int tid = threadIdx.x;
  const int w = tid >> 6;
  const int l = tid & 63;
  const int kgrp = l >> 3;
  const int cq = l & 7;
  const int kbase = w * 256 + kgrp * 32;
  const int cbase = cg * 32;
  const int c4 = cq * 4;
  const int batch0 = bg * 8;
  const int fb = tid >> 5;   // finisher batch 0..7
  const int fc = tid & 31;   // finisher col   0..31

  __shared__ float h_lds[8 * 1024] __attribute__((aligned(16)));
  __shared__ float part[4][8][32] __attribute__((aligned(16)));

  // Load this lane's Wh slice into registers (persistent across all steps)
  float4 wh4[32];
#pragma unroll
  for (int i = 0; i < 32; ++i)
    wh4[i] = *(const float4*)&Wh[(size_t)(kbase + i) * Hdim + cbase + c4];

  unsigned int* ctr = &ctrs[bg * 32];
  const size_t orow = (size_t)(batch0 + fb) * ((size_t)Tdim * Hdim) + cbase + fc;

  for (int t = 0; t < Tdim; ++t) {
    float xp = out[orow + (size_t)t * Hdim];
    float sum = 0.f;
    if (t > 0) {
      // stage h_t (8 batches x 1024) into LDS, XOR-swizzled for broadcast reads
      const float* hsrc =
          hbuf + (size_t)(t & 1) * (64 * 1024) + (size_t)batch0 * 1024;
#pragma unroll
      for (int v = 0; v < 8; ++v) {
        int L = tid * 32 + v * 4;  // 256 thr * 32 floats = 8192
        float4 hv = *(const float4*)&hsrc[L];
        int sw = L ^ ((((L & 1023) >> 5) & 7) << 2);
        *(float4*)&h_lds[sw] = hv;
      }
      __syncthreads();
#pragma unroll
      for (int b = 0; b < 8; ++b) {
        float p0 = 0.f, p1 = 0.f, p2 = 0.f, p3 = 0.f;
        const int Lb = b * 1024 + kbase;
#pragma unroll
        for (int q = 0; q < 8; ++q) {
          int sw = (Lb + q * 4) ^ (kgrp << 2);
          float4 hv = *(const float4*)&h_lds[sw];
          float4 wa = wh4[4 * q + 0], wb = wh4[4 * q + 1];
          float4 wc = wh4[4 * q + 2], wd = wh4[4 * q + 3];
          p0 = fmaf(hv.x, wa.x, p0); p0 = fmaf(hv.y, wb.x, p0);
          p0 = fmaf(hv.z, wc.x, p0); p0 = fmaf(hv.w, wd.x, p0);
          p1 = fmaf(hv.x, wa.y, p1); p1 = fmaf(hv.y, wb.y, p1);
          p1 = fmaf(hv.z, wc.y, p1); p1 = fmaf(hv.w, wd.y, p1);
          p2 = fmaf(hv.x, wa.z, p2); p2 = fmaf(hv.y, wb.z, p2);
          p2 = fmaf(hv.z, wc.z, p2); p2 = fmaf(hv.w, wd.z, p2);
          p3 = fmaf(hv.x, wa.w, p3); p3 = fmaf(hv.y, wb.w, p3);
          p3 = fmaf(hv.z, wc.w, p3); p3 = fmaf(hv.w, wd.w, p3);
        }
        // butterfly over k-groups (lane bits 3..5)
        p0 += __shfl_xor(p0, 8);  p0 += __shfl_xor(p0, 16); p0 += __shfl_xor(p0, 32);
        p1 += __shfl_xor(p1, 8);  p1 += __shfl_xor(p1, 16); p1 += __shfl_xor(p1, 32);
        p2 += __shfl_xor(p2, 8);  p2 += __shfl_xor(p2, 16); p2 += __shfl_xor(p2, 32);
        p3 += __shfl_xor(p3, 8);  p3 += __shfl_xor(p3, 16); p3 += __shfl_xor(p3, 32);
        if (kgrp == b)
          *(float4*)&part[w][b][c4] = make_float4(p0, p1, p2, p3);
      }
      __syncthreads();
      sum = part[0][fb][fc] + part[1][fb][fc] + part[2][fb][fc] + part[3][fb][fc];
    }
    float h = tanh_fast(xp + sum);
    out[orow + (size_t)t * Hdim] = h;
    hbuf[(size_t)((t + 1) & 1) * (64 * 1024) + (size_t)(batch0 + fb) * 1024 +
         cbase + fc] = h;
    if (t == Tdim - 1)
      hlast[(size_t)(batch0 + fb) * Hdim + cbase + fc] = h;

    if (t < Tdim - 1) {
      __syncthreads();  // drains vmcnt: all block stores complete to L2
      if (tid == 0) {
        __threadfence();  // release: write back this XCD's L2 (device scope)
        __hip_atomic_fetch_add(ctr, 1u, __ATOMIC_RELAXED,
                               __HIP_MEMORY_SCOPE_AGENT);
        const unsigned int target = 32u * (unsigned int)(t + 1);
        while (__hip_atomic_load(ctr, __ATOMIC_RELAXED,
                                 __HIP_MEMORY_SCOPE_AGENT) < target) {
          __builtin_amdgcn_s_sleep(1);
        }
        __threadfence();  // acquire: invalidate stale L1/L2 before h reads
      }
      __syncthreads();
      // next iteration's staging overwrites h_lds only after this barrier
    }
  }
}

extern "C" void kernel_launch(void* const* d_in, const int* in_sizes, int n_in,
                              void* d_out, int out_size, void* d_ws,
                              size_t ws_size, hipStream_t stream) {
  const float* x  = (const float*)d_in[0];
  const float* Wx = (const float*)d_in[1];
  const float* bx = (const float*)d_in[2];
  const float* Wh = (const float*)d_in[3];
  const float* bh = (const float*)d_in[4];
  float* out = (float*)d_out;
  float* hlast = out + (size_t)Bdim * Tdim * Hdim;
  unsigned int* ctrs = (unsigned int*)d_ws;
  float* hbuf = (float*)((char*)d_ws + 4096);

  // zero the cluster barrier counters (ws is NOT re-poisoned between replays)
  hipMemsetAsync(d_ws, 0, 4096, stream);

  dim3 g1(Hdim / BN, Mdim / BM);  // (8, 256)
  xproj_gemm<<<g1, dim3(256), 0, stream>>>(x, Wx, bx, bh, out);
  rnn_scan<<<dim3(256), dim3(256), 0, stream>>>(Wh, out, hlast, hbuf, ctrs);
}

// Round 2
// 4898.718 us; speedup vs baseline: 1.7501x; 1.7501x over previous
//
#include <hip/hip_runtime.h>

// RNN: B=64, T=512, I=1024, H=1024, fp32.
// Phase 1: xproj = x @ Wx + bx + bh  -> written into d_out
// Phase 2: persistent scan; 256 blocks = 8 batch-groups x 32 col-groups.
//   - Wh slice in registers (32 float4/lane) for all 512 steps
//   - h exchange: relaxed agent-scope (sc1) atomics through the coherence
//     point -- NO threadfence (no L2 wbl2/inv), NO atomic-RMW barrier.
//   - barrier: per-block flag word (monotone step counter), 32 flags in one
//     128B line; wave0 polls all 32 in parallel with one coalesced load.

#define Bdim 64
#define Tdim 512
#define Idim 1024
#define Hdim 1024
#define Mdim (Bdim * Tdim)  // 32768

__device__ __forceinline__ float tanh_fast(float x) {
  float e = __expf(2.0f * x);
  return 1.0f - 2.0f / (e + 1.0f);
}

// ---------------- Phase 1: xproj GEMM (fp32 SIMT, 128x128 tile, 8x8/thread) --
#define BM 128
#define BN 128
#define BK 16

__global__ __launch_bounds__(256) void xproj_gemm(
    const float* __restrict__ A,   // x  [M=32768][K=1024]
    const float* __restrict__ W,   // Wx [K=1024][N=1024]
    const float* __restrict__ bx,  // [N]
    const float* __restrict__ bh,  // [N]
    float* __restrict__ C) {       // [M][N]
  __shared__ float As[BK][BM];
  __shared__ float Bs[BK][BN];
  const int tid = threadIdx.x;
  const int m0 = blockIdx.y * BM;
  const int n0 = blockIdx.x * BN;
  const int ty = tid >> 4;
  const int tx = tid & 15;
  const int ar = tid & 127;
  const int ah = tid >> 7;
  const int bk = tid >> 4;
  const int bs = tid & 15;

  float acc[8][8];
#pragma unroll
  for (int i = 0; i < 8; ++i)
#pragma unroll
    for (int j = 0; j < 8; ++j) acc[i][j] = 0.f;

  for (int k0 = 0; k0 < Idim; k0 += BK) {
    float4 a0 = *(const float4*)&A[(size_t)(m0 + ar) * Idim + k0 + ah * 8];
    float4 a1 = *(const float4*)&A[(size_t)(m0 + ar) * Idim + k0 + ah * 8 + 4];
    float4 b0 = *(const float4*)&W[(size_t)(k0 + bk) * Hdim + n0 + bs * 8];
    float4 b1 = *(const float4*)&W[(size_t)(k0 + bk) * Hdim + n0 + bs * 8 + 4];
    __syncthreads();
    As[ah * 8 + 0][ar] = a0.x; As[ah * 8 + 1][ar] = a0.y;
    As[ah * 8 + 2][ar] = a0.z; As[ah * 8 + 3][ar] = a0.w;
    As[ah * 8 + 4][ar] = a1.x; As[ah * 8 + 5][ar] = a1.y;
    As[ah * 8 + 6][ar] = a1.z; As[ah * 8 + 7][ar] = a1.w;
    *(float4*)&Bs[bk][bs * 8] = b0;
    *(float4*)&Bs[bk][bs * 8 + 4] = b1;
    __syncthreads();
#pragma unroll
    for (int kk = 0; kk < BK; ++kk) {
      float4 x0 = *(const float4*)&As[kk][ty * 8];
      float4 x1 = *(const float4*)&As[kk][ty * 8 + 4];
      float4 y0 = *(const float4*)&Bs[kk][tx * 8];
      float4 y1 = *(const float4*)&Bs[kk][tx * 8 + 4];
      float av[8] = {x0.x, x0.y, x0.z, x0.w, x1.x, x1.y, x1.z, x1.w};
      float bv[8] = {y0.x, y0.y, y0.z, y0.w, y1.x, y1.y, y1.z, y1.w};
#pragma unroll
      for (int i = 0; i < 8; ++i)
#pragma unroll
        for (int j = 0; j < 8; ++j)
          acc[i][j] = fmaf(av[i], bv[j], acc[i][j]);
    }
  }
  float bias[8];
#pragma unroll
  for (int j = 0; j < 8; ++j) bias[j] = bx[n0 + tx * 8 + j] + bh[n0 + tx * 8 + j];
#pragma unroll
  for (int i = 0; i < 8; ++i) {
    float4 o0, o1;
    o0.x = acc[i][0] + bias[0]; o0.y = acc[i][1] + bias[1];
    o0.z = acc[i][2] + bias[2]; o0.w = acc[i][3] + bias[3];
    o1.x = acc[i][4] + bias[4]; o1.y = acc[i][5] + bias[5];
    o1.z = acc[i][6] + bias[6]; o1.w = acc[i][7] + bias[7];
    size_t off = (size_t)(m0 + ty * 8 + i) * Hdim + n0 + tx * 8;
    *(float4*)&C[off] = o0;
    *(float4*)&C[off + 4] = o1;
  }
}

// ---------------- Phase 2: persistent recurrent scan ------------------------
__global__ __launch_bounds__(256, 1) void rnn_scan(
    const float* __restrict__ Wh,   // [H][H]
    float* __restrict__ out,        // [B][T][H]: xproj in, h out
    float* __restrict__ hlast,      // [B][H]
    float* hbuf,                    // ws: [2][64][1024]
    unsigned int* flags) {          // ws: [8][32] per-block step counters
  const int bid = blockIdx.x;
  const int bg = bid & 7;          // batch group (8 batches)
  const int cg = bid >> 3;         // col group (32 cols)
  const int tid = threadIdx.x;
  const int w = tid >> 6;
  const int l = tid & 63;
  const int kgrp = l >> 3;
  const int cq = l & 7;
  const int kbase = w * 256 + kgrp * 32;
  const int cbase = cg * 32;
  const int c4 = cq * 4;
  const int batch0 = bg * 8;
  const int fb = tid >> 5;         // finisher batch 0..7
  const int fc = tid & 31;         // finisher col   0..31

  __shared__ float h_lds[8 * 1024] __attribute__((aligned(16)));
  __shared__ float part[4][8][32] __attribute__((aligned(16)));

  // Persistent Wh slice: lane holds Wh[kbase..+31][cbase+c4..+3]
  float4 wh4[32];
#pragma unroll
  for (int i = 0; i < 32; ++i)
    wh4[i] = *(const float4*)&Wh[(size_t)(kbase + i) * Hdim + cbase + c4];

  unsigned int* myflags = &flags[bg * 32];
  const size_t orow = (size_t)(batch0 + fb) * ((size_t)Tdim * Hdim) + cbase + fc;
  const size_t hrow = (size_t)(batch0 + fb) * Hdim + cbase + fc;

  float xp = out[orow];  // xproj for t=0
  float sum = 0.f;

  for (int t = 0; t < Tdim; ++t) {
    float h = tanh_fast(xp + sum);
    __builtin_nontemporal_store(h, &out[orow + (size_t)t * Hdim]);
    if (t == Tdim - 1) {
      hlast[hrow] = h;
      break;
    }
    // publish h (write-through to coherence point; no L2 state to flush)
    float* hdst = hbuf + (size_t)((t + 1) & 1) * (64 * 1024);
    __hip_atomic_store(&hdst[hrow], h, __ATOMIC_RELAXED,
                       __HIP_MEMORY_SCOPE_AGENT);
    __syncthreads();  // compiler emits s_waitcnt vmcnt(0): all h-stores acked
    if (tid == 0)
      __hip_atomic_store(&myflags[cg], (unsigned int)(t + 1), __ATOMIC_RELAXED,
                         __HIP_MEMORY_SCOPE_AGENT);
    // prefetch next xproj while polling
    xp = __builtin_nontemporal_load(&out[orow + (size_t)(t + 1) * Hdim]);
    if (w == 0) {
      const unsigned int tgt = (unsigned int)(t + 1);
      unsigned int* f = &myflags[l & 31];
      while (true) {
        unsigned int v =
            __hip_atomic_load(f, __ATOMIC_RELAXED, __HIP_MEMORY_SCOPE_AGENT);
        if (__ballot(v >= tgt) == ~0ull) break;
        __builtin_amdgcn_s_sleep(1);
      }
    }
    __syncthreads();
    // stage cluster h (8 batches x 1024) into LDS, XOR-swizzled
    const float* hsrc = hbuf + (size_t)((t + 1) & 1) * (64 * 1024) +
                        (size_t)batch0 * Hdim;
#pragma unroll
    for (int v = 0; v < 8; ++v) {
      int L = tid * 32 + v * 4;  // 256 thr * 32 floats = 8192
      unsigned long long d0 = __hip_atomic_load(
          (const unsigned long long*)&hsrc[L], __ATOMIC_RELAXED,
          __HIP_MEMORY_SCOPE_AGENT);
      unsigned long long d1 = __hip_atomic_load(
          (const unsigned long long*)&hsrc[L + 2], __ATOMIC_RELAXED,
          __HIP_MEMORY_SCOPE_AGENT);
      int sw = L ^ (((L >> 5) & 7) << 2);
      *(unsigned long long*)&h_lds[sw] = d0;
      *(unsigned long long*)&h_lds[sw + 2] = d1;
    }
    __syncthreads();
    // sum_{k} h[b][k] * Wh[k][c] for this block's 8 batches x 32 cols
#pragma unroll
    for (int b = 0; b < 8; ++b) {
      float p0 = 0.f, p1 = 0.f, p2 = 0.f, p3 = 0.f;
      const int Lb = b * 1024 + kbase;
#pragma unroll
      for (int q = 0; q < 8; ++q) {
        int sw = (Lb + q * 4) ^ (kgrp << 2);
        float4 hv = *(const float4*)&h_lds[sw];
        float4 wa = wh4[4 * q + 0], wb = wh4[4 * q + 1];
        float4 wc = wh4[4 * q + 2], wd = wh4[4 * q + 3];
        p0 = fmaf(hv.x, wa.x, p0); p0 = fmaf(hv.y, wb.x, p0);
        p0 = fmaf(hv.z, wc.x, p0); p0 = fmaf(hv.w, wd.x, p0);
        p1 = fmaf(hv.x, wa.y, p1); p1 = fmaf(hv.y, wb.y, p1);
        p1 = fmaf(hv.z, wc.y, p1); p1 = fmaf(hv.w, wd.y, p1);
        p2 = fmaf(hv.x, wa.z, p2); p2 = fmaf(hv.y, wb.z, p2);
        p2 = fmaf(hv.z, wc.z, p2); p2 = fmaf(hv.w, wd.z, p2);
        p3 = fmaf(hv.x, wa.w, p3); p3 = fmaf(hv.y, wb.w, p3);
        p3 = fmaf(hv.z, wc.w, p3); p3 = fmaf(hv.w, wd.w, p3);
      }
      p0 += __shfl_xor(p0, 8);  p0 += __shfl_xor(p0, 16); p0 += __shfl_xor(p0, 32);
      p1 += __shfl_xor(p1, 8);  p1 += __shfl_xor(p1, 16); p1 += __shfl_xor(p1, 32);
      p2 += __shfl_xor(p2, 8);  p2 += __shfl_xor(p2, 16); p2 += __shfl_xor(p2, 32);
      p3 += __shfl_xor(p3, 8);  p3 += __shfl_xor(p3, 16); p3 += __shfl_xor(p3, 32);
      if (kgrp == b)
        *(float4*)&part[w][b][c4] = make_float4(p0, p1, p2, p3);
    }
    __syncthreads();
    sum = part[0][fb][fc] + part[1][fb][fc] + part[2][fb][fc] + part[3][fb][fc];
  }
}

extern "C" void kernel_launch(void* const* d_in, const int* in_sizes, int n_in,
                              void* d_out, int out_size, void* d_ws,
                              size_t ws_size, hipStream_t stream) {
  const float* x  = (const float*)d_in[0];
  const float* Wx = (const float*)d_in[1];
  const float* bx = (const float*)d_in[2];
  const float* Wh = (const float*)d_in[3];
  const float* bh = (const float*)d_in[4];
  float* out = (float*)d_out;
  float* hlast = out + (size_t)Bdim * Tdim * Hdim;
  unsigned int* flags = (unsigned int*)d_ws;
  float* hbuf = (float*)((char*)d_ws + 4096);

  // zero the flag array each launch (ws is NOT re-poisoned between replays)
  hipMemsetAsync(d_ws, 0, 4096, stream);

  dim3 g1(Hdim / BN, Mdim / BM);  // (8, 256)
  xproj_gemm<<<g1, dim3(256), 0, stream>>>(x, Wx, bx, bh, out);
  rnn_scan<<<dim3(256), dim3(256), 0, stream>>>(Wh, out, hlast, hbuf, flags);
}